// Round 1
// baseline (247.979 us; speedup 1.0000x reference)
//
#include <hip/hip_runtime.h>
#include <hip/hip_bf16.h>
#include <math.h>

typedef short short8 __attribute__((ext_vector_type(8)));
typedef float f32x4 __attribute__((ext_vector_type(4)));

#define NE 500000
#define ND 128

static __device__ __forceinline__ unsigned short f2bf(float f) {
    unsigned u = __builtin_bit_cast(unsigned, f);
    u += 0x7FFFu + ((u >> 16) & 1u);   // round-to-nearest-even
    return (unsigned short)(u >> 16);
}

// W1 [K=256][N=256] f32  ->  W1T [N=256][K=256] bf16 (k-contiguous rows)
__global__ void prep_w1t_kernel(const float* __restrict__ W1,
                                unsigned short* __restrict__ W1T) {
    int i = blockIdx.x * blockDim.x + threadIdx.x;   // 0..65535
    int n = i >> 8, k = i & 255;
    W1T[n * 256 + k] = f2bf(W1[k * 256 + n]);
}

__global__ __launch_bounds__(256) void edge_mlp_kernel(
    const float* __restrict__ z, const float* __restrict__ z2,
    const int* __restrict__ edge,
    const unsigned short* __restrict__ w1t,
    const float* __restrict__ b1, const float* __restrict__ W2,
    const float* __restrict__ b2, float* __restrict__ out)
{
    __shared__ unsigned short xs[64 * 256];   // 32 KB, XOR-swizzled bf16 x-tile
    __shared__ float partials[4][64];

    const int tid = threadIdx.x;
    const int lane = tid & 63;
    const int wave = tid >> 6;        // n-slice owner: cols [wave*64, wave*64+64)
    const int l15 = lane & 15;
    const int l4 = lane >> 4;
    const long eb0 = (long)blockIdx.x * 64;

    // ---- phase 1: gather + multiply -> bf16 x tile in LDS ----
    {
        const int el = tid >> 2;      // edge-in-block 0..63
        const int part = tid & 3;     // 64 k's each
        long e = eb0 + el;
        int ec = (e < NE) ? (int)e : 0;
        int si = edge[ec];
        int di = edge[NE + ec];
        const float* ps;
        const float* pd;
        if (part < 2) {
            ps = z + (long)si * ND + part * 64;
            pd = z + (long)di * ND + part * 64;
        } else {
            ps = z2 + (long)si * ND + (part - 2) * 64;
            pd = z2 + (long)di * ND + (part - 2) * 64;
        }
        const int kbase = part * 64;
        const int swz = (el & 7) << 3;
#pragma unroll
        for (int c = 0; c < 64; c += 8) {
            float4 a0 = *reinterpret_cast<const float4*>(ps + c);
            float4 a1 = *reinterpret_cast<const float4*>(ps + c + 4);
            float4 c0 = *reinterpret_cast<const float4*>(pd + c);
            float4 c1 = *reinterpret_cast<const float4*>(pd + c + 4);
            short8 v;
            v[0] = (short)f2bf(a0.x * c0.x);
            v[1] = (short)f2bf(a0.y * c0.y);
            v[2] = (short)f2bf(a0.z * c0.z);
            v[3] = (short)f2bf(a0.w * c0.w);
            v[4] = (short)f2bf(a1.x * c1.x);
            v[5] = (short)f2bf(a1.y * c1.y);
            v[6] = (short)f2bf(a1.z * c1.z);
            v[7] = (short)f2bf(a1.w * c1.w);
            int k = kbase + c;
            *reinterpret_cast<short8*>(&xs[el * 256 + (k ^ swz)]) = v;
        }
    }
    __syncthreads();

    // ---- phase 2: X[64x256] @ W1[256x256] ; per-wave 64x64 output slice ----
    f32x4 acc[4][4];
#pragma unroll
    for (int m = 0; m < 4; ++m)
#pragma unroll
        for (int n = 0; n < 4; ++n)
            acc[m][n] = (f32x4){0.f, 0.f, 0.f, 0.f};

    const int ncol0 = wave * 64 + l15;
#pragma unroll
    for (int ks = 0; ks < 8; ++ks) {
        const int k0 = ks * 32 + l4 * 8;
        short8 a[4], b[4];
#pragma unroll
        for (int m = 0; m < 4; ++m) {
            int row = m * 16 + l15;
            a[m] = *reinterpret_cast<const short8*>(
                &xs[row * 256 + (k0 ^ ((row & 7) << 3))]);
        }
#pragma unroll
        for (int n = 0; n < 4; ++n) {
            b[n] = *reinterpret_cast<const short8*>(
                w1t + (long)(ncol0 + n * 16) * 256 + k0);
        }
#pragma unroll
        for (int m = 0; m < 4; ++m)
#pragma unroll
            for (int n = 0; n < 4; ++n)
                acc[m][n] = __builtin_amdgcn_mfma_f32_16x16x32_bf16(
                    a[m], b[n], acc[m][n], 0, 0, 0);
    }

    // ---- phase 3: fused relu + dot(W2) + sigmoid epilogue ----
    float b1v[4], w2v[4];
#pragma unroll
    for (int n = 0; n < 4; ++n) {
        int col = wave * 64 + n * 16 + l15;
        b1v[n] = b1[col];
        w2v[n] = W2[col];
    }
#pragma unroll
    for (int m = 0; m < 4; ++m) {
        float s0 = 0.f, s1 = 0.f, s2 = 0.f, s3 = 0.f;
#pragma unroll
        for (int n = 0; n < 4; ++n) {
            float h0 = fmaxf(acc[m][n][0] + b1v[n], 0.f);
            float h1 = fmaxf(acc[m][n][1] + b1v[n], 0.f);
            float h2 = fmaxf(acc[m][n][2] + b1v[n], 0.f);
            float h3 = fmaxf(acc[m][n][3] + b1v[n], 0.f);
            s0 += h0 * w2v[n]; s1 += h1 * w2v[n];
            s2 += h2 * w2v[n]; s3 += h3 * w2v[n];
        }
#pragma unroll
        for (int mask = 1; mask < 16; mask <<= 1) {
            s0 += __shfl_xor(s0, mask, 64);
            s1 += __shfl_xor(s1, mask, 64);
            s2 += __shfl_xor(s2, mask, 64);
            s3 += __shfl_xor(s3, mask, 64);
        }
        if (l15 == 0) {
            int rb = m * 16 + l4 * 4;
            partials[wave][rb + 0] = s0;
            partials[wave][rb + 1] = s1;
            partials[wave][rb + 2] = s2;
            partials[wave][rb + 3] = s3;
        }
    }
    __syncthreads();

    if (tid < 64) {
        float p = partials[0][tid] + partials[1][tid]
                + partials[2][tid] + partials[3][tid] + b2[0];
        long e = eb0 + tid;
        if (e < NE) out[e] = 1.0f / (1.0f + expf(-p));
    }
}

extern "C" void kernel_launch(void* const* d_in, const int* in_sizes, int n_in,
                              void* d_out, int out_size, void* d_ws, size_t ws_size,
                              hipStream_t stream)
{
    const float* z  = (const float*)d_in[0];
    const float* z2 = (const float*)d_in[1];
    const int*  edge = (const int*)d_in[2];
    const float* W1 = (const float*)d_in[3];
    const float* b1 = (const float*)d_in[4];
    const float* W2 = (const float*)d_in[5];
    const float* b2 = (const float*)d_in[6];
    float* out = (float*)d_out;
    unsigned short* w1t = (unsigned short*)d_ws;   // 128 KB

    prep_w1t_kernel<<<256, 256, 0, stream>>>(W1, w1t);
    const int nblk = (NE + 63) / 64;   // 7813
    edge_mlp_kernel<<<nblk, 256, 0, stream>>>(z, z2, edge, w1t, b1, W2, b2, out);
}

// Round 2
// 199.117 us; speedup vs baseline: 1.2454x; 1.2454x over previous
//
#include <hip/hip_runtime.h>
#include <hip/hip_bf16.h>
#include <math.h>

typedef short short8 __attribute__((ext_vector_type(8)));
typedef short short4v __attribute__((ext_vector_type(4)));
typedef float f32x4 __attribute__((ext_vector_type(4)));

#define NE 500000
#define ND 128
#define NNODES 100000

static __device__ __forceinline__ unsigned short f2bf(float f) {
    unsigned u = __builtin_bit_cast(unsigned, f);
    u += 0x7FFFu + ((u >> 16) & 1u);   // round-to-nearest-even
    return (unsigned short)(u >> 16);
}
static __device__ __forceinline__ float bf2f(unsigned short h) {
    return __builtin_bit_cast(float, (unsigned)h << 16);
}

// W1 [K=256][N=256] f32  ->  W1T [N=256][K=256] bf16 (k-contiguous rows)
__global__ void prep_w1t_kernel(const float* __restrict__ W1,
                                unsigned short* __restrict__ W1T) {
    int i = blockIdx.x * blockDim.x + threadIdx.x;   // 0..65535
    int n = i >> 8, k = i & 255;
    W1T[n * 256 + k] = f2bf(W1[k * 256 + n]);
}

// z, z2 f32 -> bf16 mirrors (8 elems/thread)
__global__ __launch_bounds__(256) void prep_zbf_kernel(
    const float* __restrict__ z, const float* __restrict__ z2,
    unsigned short* __restrict__ zbf, unsigned short* __restrict__ z2bf) {
    long t = (long)blockIdx.x * 256 + threadIdx.x;   // 0..3,199,999
    const float* src; unsigned short* dst; long off;
    const long half = (long)NNODES * ND / 8;         // 1,600,000
    if (t < half) { src = z;  dst = zbf;  off = t * 8; }
    else          { src = z2; dst = z2bf; off = (t - half) * 8; }
    float4 a = *reinterpret_cast<const float4*>(src + off);
    float4 b = *reinterpret_cast<const float4*>(src + off + 4);
    short8 v;
    v[0] = (short)f2bf(a.x); v[1] = (short)f2bf(a.y);
    v[2] = (short)f2bf(a.z); v[3] = (short)f2bf(a.w);
    v[4] = (short)f2bf(b.x); v[5] = (short)f2bf(b.y);
    v[6] = (short)f2bf(b.z); v[7] = (short)f2bf(b.w);
    *reinterpret_cast<short8*>(dst + off) = v;
}

template <bool BF16P>
__global__ __launch_bounds__(256) void edge_mlp_kernel(
    const float* __restrict__ z, const float* __restrict__ z2,
    const unsigned short* __restrict__ zbf, const unsigned short* __restrict__ z2bf,
    const int* __restrict__ edge,
    const unsigned short* __restrict__ w1t,
    const float* __restrict__ b1, const float* __restrict__ W2,
    const float* __restrict__ b2, float* __restrict__ out)
{
    __shared__ unsigned short xs[64 * 256];   // 32 KB, XOR-swizzled bf16 x-tile
    __shared__ float partials[4][64];
    __shared__ int sidx[64], didx[64];

    const int tid = threadIdx.x;
    const int lane = tid & 63;
    const int wv = tid >> 6;
    const int l15 = lane & 15;
    const int l4 = lane >> 4;
    const long eb0 = (long)blockIdx.x * 64;

    // ---- preload edge indices (coalesced) ----
    if (tid < 64) {
        long e = eb0 + tid;
        sidx[tid] = edge[(e < NE) ? e : 0];
    } else if (tid < 128) {
        int t = tid - 64;
        long e = eb0 + t;
        didx[t] = edge[NE + ((e < NE) ? e : 0)];
    }
    __syncthreads();

    // ---- phase 1: coalesced gather + multiply -> bf16 x tile in LDS ----
    if (BF16P) {
        // per instruction: 2 edges; lanes 0-15: z half of e0, 16-31: z2 of e0,
        // 32-47: z of e1, 48-63: z2 of e1. Each lane owns 8 contiguous cols.
        const int l5 = lane >> 5;          // which edge of the pair
        const int half = (lane >> 4) & 1;  // z vs z2
        const int c8 = lane & 15;          // 8-col chunk
        const unsigned short* base = half ? z2bf : zbf;
#pragma unroll
        for (int i = 0; i < 8; ++i) {
            int el = (wv << 4) + (i << 1) + l5;
            int s = sidx[el], d = didx[el];
            short8 vs = *reinterpret_cast<const short8*>(base + (long)s * ND + (c8 << 3));
            short8 vd = *reinterpret_cast<const short8*>(base + (long)d * ND + (c8 << 3));
            short8 p;
#pragma unroll
            for (int j = 0; j < 8; ++j)
                p[j] = (short)f2bf(bf2f((unsigned short)vs[j]) * bf2f((unsigned short)vd[j]));
            int col0 = (half << 7) + (c8 << 3);
            *reinterpret_cast<short8*>(&xs[el * 256 + (col0 ^ ((el & 7) << 3))]) = p;
        }
    } else {
        // f32 fallback: per instruction one edge; lanes 0-31: z row, 32-63: z2 row
        const int half = lane >> 5;
        const int c4 = lane & 31;          // 4-col chunk
        const float* base = half ? z2 : z;
#pragma unroll
        for (int i = 0; i < 16; ++i) {
            int el = (wv << 4) + i;
            int s = sidx[el], d = didx[el];
            float4 a = *reinterpret_cast<const float4*>(base + (long)s * ND + (c4 << 2));
            float4 b = *reinterpret_cast<const float4*>(base + (long)d * ND + (c4 << 2));
            short4v p;
            p[0] = (short)f2bf(a.x * b.x); p[1] = (short)f2bf(a.y * b.y);
            p[2] = (short)f2bf(a.z * b.z); p[3] = (short)f2bf(a.w * b.w);
            int col0 = (half << 7) + (c4 << 2);
            *reinterpret_cast<short4v*>(&xs[el * 256 + (col0 ^ ((el & 7) << 3))]) = p;
        }
    }
    __syncthreads();

    // ---- phase 2: X[64x256] @ W1[256x256] ; per-wave 64x64 output slice ----
    f32x4 acc[4][4];
#pragma unroll
    for (int m = 0; m < 4; ++m)
#pragma unroll
        for (int n = 0; n < 4; ++n)
            acc[m][n] = (f32x4){0.f, 0.f, 0.f, 0.f};

    const int ncol0 = wv * 64 + l15;
#pragma unroll
    for (int ks = 0; ks < 8; ++ks) {
        const int k0 = ks * 32 + l4 * 8;
        short8 a[4], b[4];
#pragma unroll
        for (int m = 0; m < 4; ++m) {
            int row = m * 16 + l15;
            a[m] = *reinterpret_cast<const short8*>(
                &xs[row * 256 + (k0 ^ ((row & 7) << 3))]);
        }
#pragma unroll
        for (int n = 0; n < 4; ++n) {
            b[n] = *reinterpret_cast<const short8*>(
                w1t + (long)(ncol0 + n * 16) * 256 + k0);
        }
#pragma unroll
        for (int m = 0; m < 4; ++m)
#pragma unroll
            for (int n = 0; n < 4; ++n)
                acc[m][n] = __builtin_amdgcn_mfma_f32_16x16x32_bf16(
                    a[m], b[n], acc[m][n], 0, 0, 0);
    }

    // ---- phase 3: fused relu + dot(W2) + sigmoid epilogue ----
    float b1v[4], w2v[4];
#pragma unroll
    for (int n = 0; n < 4; ++n) {
        int col = wv * 64 + n * 16 + l15;
        b1v[n] = b1[col];
        w2v[n] = W2[col];
    }
#pragma unroll
    for (int m = 0; m < 4; ++m) {
        float s0 = 0.f, s1 = 0.f, s2 = 0.f, s3 = 0.f;
#pragma unroll
        for (int n = 0; n < 4; ++n) {
            float h0 = fmaxf(acc[m][n][0] + b1v[n], 0.f);
            float h1 = fmaxf(acc[m][n][1] + b1v[n], 0.f);
            float h2 = fmaxf(acc[m][n][2] + b1v[n], 0.f);
            float h3 = fmaxf(acc[m][n][3] + b1v[n], 0.f);
            s0 += h0 * w2v[n]; s1 += h1 * w2v[n];
            s2 += h2 * w2v[n]; s3 += h3 * w2v[n];
        }
#pragma unroll
        for (int mask = 1; mask < 16; mask <<= 1) {
            s0 += __shfl_xor(s0, mask, 64);
            s1 += __shfl_xor(s1, mask, 64);
            s2 += __shfl_xor(s2, mask, 64);
            s3 += __shfl_xor(s3, mask, 64);
        }
        if (l15 == 0) {
            int rb = m * 16 + l4 * 4;
            partials[wv][rb + 0] = s0;
            partials[wv][rb + 1] = s1;
            partials[wv][rb + 2] = s2;
            partials[wv][rb + 3] = s3;
        }
    }
    __syncthreads();

    if (tid < 64) {
        float p = partials[0][tid] + partials[1][tid]
                + partials[2][tid] + partials[3][tid] + b2[0];
        long e = eb0 + tid;
        if (e < NE) out[e] = 1.0f / (1.0f + expf(-p));
    }
}

extern "C" void kernel_launch(void* const* d_in, const int* in_sizes, int n_in,
                              void* d_out, int out_size, void* d_ws, size_t ws_size,
                              hipStream_t stream)
{
    const float* z  = (const float*)d_in[0];
    const float* z2 = (const float*)d_in[1];
    const int*  edge = (const int*)d_in[2];
    const float* W1 = (const float*)d_in[3];
    const float* b1 = (const float*)d_in[4];
    const float* W2 = (const float*)d_in[5];
    const float* b2 = (const float*)d_in[6];
    float* out = (float*)d_out;

    const size_t zbf_bytes = (size_t)NNODES * ND * 2;        // 25.6 MB each
    const size_t need = 2 * zbf_bytes + 256 * 256 * 2;       // + w1t
    const bool usebf16 = (ws_size >= need);

    unsigned short* zbf  = (unsigned short*)d_ws;
    unsigned short* z2bf = (unsigned short*)((char*)d_ws + zbf_bytes);
    unsigned short* w1t  = usebf16
        ? (unsigned short*)((char*)d_ws + 2 * zbf_bytes)
        : (unsigned short*)d_ws;

    prep_w1t_kernel<<<256, 256, 0, stream>>>(W1, w1t);
    if (usebf16) {
        prep_zbf_kernel<<<12500, 256, 0, stream>>>(z, z2, zbf, z2bf);
        const int nblk = (NE + 63) / 64;
        edge_mlp_kernel<true><<<nblk, 256, 0, stream>>>(
            z, z2, zbf, z2bf, edge, w1t, b1, W2, b2, out);
    } else {
        const int nblk = (NE + 63) / 64;
        edge_mlp_kernel<false><<<nblk, 256, 0, stream>>>(
            z, z2, zbf, z2bf, edge, w1t, b1, W2, b2, out);
    }
}